// Round 1
// baseline (568.624 us; speedup 1.0000x reference)
//
#include <hip/hip_runtime.h>
#include <hip/hip_bf16.h>

#define DEVI __device__ __forceinline__

typedef __attribute__((ext_vector_type(8))) __bf16 bf16x8;
typedef __attribute__((ext_vector_type(4))) float f32x4;

using bf16 = __hip_bfloat16;

DEVI float bf2f(bf16 v) { return __bfloat162float(v); }
DEVI bf16 f2bf(float v) { return __float2bfloat16(v); }

DEVI float gelu_exact(float v) {
    return 0.5f * v * (1.0f + erff(v * 0.70710678118654752f));
}

DEVI void async16(void* lds, const void* g) {
    __builtin_amdgcn_global_load_lds(
        (const __attribute__((address_space(1))) void*)g,
        (__attribute__((address_space(3))) void*)lds, 16, 0, 0);
}

// sign of e_i * e_j in 16-dim Cayley-Dickson algebra (index is i^j)
DEVI int cd_sign(int i, int j) {
    int s = 1, n = 16;
    while (n > 1) {
        int h = n >> 1;
        int ih = (i >= h), jh = (j >= h);
        if (!ih && !jh) {
            // recurse (i, j, h)
        } else if (!ih && jh) {
            int ni = j - h, nj = i;      // (d*a): cd(j-h, i, h)
            i = ni; j = nj;
        } else if (ih && !jh) {
            if (j != 0) s = -s;          // b*conj(c)
            i = i - h;                   // cd(i-h, j, h)
        } else {
            int ni = j - h, nj = i - h;  // -conj(d)*b: cd(j-h, i-h, h)
            if (ni == 0) s = -s;
            i = ni; j = nj;
        }
        n = h;
    }
    return s;
}

// ---------------- prep: build A_T (2048x2048 bf16), row (k,d), col (i,c) ----
__global__ __launch_bounds__(256) void k_prep_A(const float* __restrict__ sed_w,
                                                bf16* __restrict__ At) {
    __shared__ float tile[128][129];
    int bi = blockIdx.x;  // 0..255
    int i = bi >> 4, k = bi & 15;
    int j = i ^ k;
    float s = (float)cd_sign(i, j);
    int t = threadIdx.x;
    int lo = t & 127, hi = t >> 7;
    const float* src = sed_w + j * 16384;
    for (int it = 0; it < 64; ++it) {
        int c = it * 2 + hi;
        tile[c][lo] = src[c * 128 + lo];
    }
    __syncthreads();
    for (int it = 0; it < 64; ++it) {
        int d = it * 2 + hi;
        At[(long)(k * 128 + d) * 2048 + i * 128 + lo] = f2bf(s * tile[lo][d]);
    }
}

// ---------------- prep: bf16 transposed weights -----------------------------
__global__ __launch_bounds__(256) void k_prep_w(const float* __restrict__ wp,
                                                const float* __restrict__ w1,
                                                const float* __restrict__ w2,
                                                bf16* __restrict__ wpT,
                                                bf16* __restrict__ w1T,
                                                bf16* __restrict__ w2T) {
    int idx = blockIdx.x * 256 + threadIdx.x;
    if (idx < 16384) {
        int d = idx >> 7, c = idx & 127;
        wpT[idx] = f2bf(wp[c * 128 + d]);              // wpT[d][c] = wp[c][d]
    } else if (idx < 16384 + 65536) {
        int e = idx - 16384;
        int o = e >> 7, c = e & 127;
        w1T[e] = f2bf(w1[c * 512 + o]);                // w1T[o][c] = w1[c][o]
    } else if (idx < 16384 + 131072) {
        int e = idx - 81920;
        int o = e >> 9, c = e & 511;
        w2T[e] = f2bf(w2[c * 128 + o]);                // w2T[o][c] = w2[c][o]
    }
}

// ---------------- LN1 + transpose to window-permuted token order ------------
// x: (B=8, C=128, H=128, W=128) fp32 -> xt (tok x 128) bf16, xn (tok x 128) bf16
__global__ __launch_bounds__(256) void k_ln1(const float* __restrict__ x,
                                             const float* __restrict__ g,
                                             const float* __restrict__ bta,
                                             bf16* __restrict__ xt,
                                             bf16* __restrict__ xn) {
    __shared__ float tile[128][128];   // [ch][c]
    __shared__ float ps[2][128], pss[2][128];
    int b = blockIdx.x >> 7, r = blockIdx.x & 127;
    int t = threadIdx.x, c = t & 127, half = t >> 7;
    const float* xb = x + ((long)b * 128 * 128 + r) * 128;
    for (int it = 0; it < 64; ++it) {
        int ch = it * 2 + half;
        tile[ch][c] = xb[(long)ch * 16384 + c];
    }
    __syncthreads();
    float s = 0.f, ss = 0.f;
    for (int ch = half * 64; ch < half * 64 + 64; ++ch) {
        float v = tile[ch][c];
        s += v; ss += v * v;
    }
    ps[half][c] = s; pss[half][c] = ss;
    __syncthreads();
    float S = ps[0][c] + ps[1][c], SS = pss[0][c] + pss[1][c];
    float mean = S * (1.f / 128.f);
    float var = SS * (1.f / 128.f) - mean * mean;
    float rstd = rsqrtf(var + 1e-5f);
    long n = (((long)b * 32 + (r >> 2)) * 32 + (c >> 2)) * 16 + ((r & 3) * 4 + (c & 3));
    bf16* xtr = xt + n * 128;
    bf16* xnr = xn + n * 128;
    for (int ch = half * 64; ch < half * 64 + 64; ++ch) {
        float v = tile[ch][c];
        xtr[ch] = f2bf(v);
        xnr[ch] = f2bf((v - mean) * rstd * g[ch] + bta[ch]);
    }
}

// ---------------- GEMM: C[M][N] = act(A[M][K] @ Bt[N][K]^T + bias) (+res) ---
// block: 128x128 tile, 4 waves each 64x64, BK=32, mfma 16x16x32 bf16
template <int ACT, int RES, int OF32>
__global__ __launch_bounds__(256) void k_gemm(const bf16* __restrict__ A,
                                              const bf16* __restrict__ Bt,
                                              const float* __restrict__ bias,
                                              const bf16* __restrict__ res,
                                              void* __restrict__ out,
                                              int K, int N) {
    __shared__ __align__(16) bf16 lA[128 * 32];
    __shared__ __align__(16) bf16 lB[128 * 32];
    int t = threadIdx.x;
    long bm = (long)blockIdx.y * 128;
    long bn = (long)blockIdx.x * 128;
    int lane = t & 63;
    int wm = ((t >> 7) & 1) * 64;
    int wn = ((t >> 6) & 1) * 64;
    int l15 = lane & 15, quad = lane >> 4;

    f32x4 acc[4][4] = {};

    int rowA = t >> 2;
    int seg = (t & 3) * 8;
    const bf16* gA = A + (bm + rowA) * (long)K + seg;
    const bf16* gB = Bt + (bn + rowA) * (long)K + seg;

    for (int k0 = 0; k0 < K; k0 += 32) {
        async16(&lA[t * 8], gA + k0);
        async16(&lA[2048 + t * 8], gA + (long)64 * K + k0);
        async16(&lB[t * 8], gB + k0);
        async16(&lB[2048 + t * 8], gB + (long)64 * K + k0);
        __syncthreads();
        bf16x8 af[4], bfr[4];
#pragma unroll
        for (int tm = 0; tm < 4; ++tm)
            af[tm] = *(const bf16x8*)&lA[(wm + tm * 16 + l15) * 32 + quad * 8];
#pragma unroll
        for (int tn = 0; tn < 4; ++tn)
            bfr[tn] = *(const bf16x8*)&lB[(wn + tn * 16 + l15) * 32 + quad * 8];
#pragma unroll
        for (int tm = 0; tm < 4; ++tm)
#pragma unroll
            for (int tn = 0; tn < 4; ++tn)
                acc[tm][tn] = __builtin_amdgcn_mfma_f32_16x16x32_bf16(
                    af[tm], bfr[tn], acc[tm][tn], 0, 0, 0);
        __syncthreads();
    }

    long No = N;
#pragma unroll
    for (int tn = 0; tn < 4; ++tn) {
        long col = bn + wn + tn * 16 + l15;
        float bv = bias ? bias[col] : 0.f;
#pragma unroll
        for (int tm = 0; tm < 4; ++tm) {
            long r0 = bm + wm + tm * 16 + quad * 4;
#pragma unroll
            for (int reg = 0; reg < 4; ++reg) {
                long r = r0 + reg;
                float v = acc[tm][tn][reg] + bv;
                if (ACT) v = gelu_exact(v);
                if (RES) v += bf2f(res[r * No + col]);
                if (OF32)
                    ((float*)out)[r * No + col] = v;
                else
                    ((bf16*)out)[r * No + col] = f2bf(v);
            }
        }
    }
}

// ---------------- LN2 (token-major, one wave per token) ---------------------
__global__ __launch_bounds__(256) void k_ln2(const bf16* __restrict__ y2,
                                             const float* __restrict__ g,
                                             const float* __restrict__ bta,
                                             bf16* __restrict__ m) {
    int t = threadIdx.x;
    long token = (long)blockIdx.x * 4 + (t >> 6);
    int lane = t & 63;
    const unsigned* ry = (const unsigned*)(y2 + token * 128);
    unsigned p = ry[lane];
    float v0 = __uint_as_float(p << 16);
    float v1 = __uint_as_float(p & 0xffff0000u);
    float s = v0 + v1, ss = v0 * v0 + v1 * v1;
#pragma unroll
    for (int off = 32; off > 0; off >>= 1) {
        s += __shfl_xor(s, off);
        ss += __shfl_xor(ss, off);
    }
    float mean = s * (1.f / 128.f);
    float var = ss * (1.f / 128.f) - mean * mean;
    float rstd = rsqrtf(var + 1e-5f);
    int ch = lane * 2;
    bf16* mr = m + token * 128;
    mr[ch] = f2bf((v0 - mean) * rstd * g[ch] + bta[ch]);
    mr[ch + 1] = f2bf((v1 - mean) * rstd * g[ch + 1] + bta[ch + 1]);
}

// ---------------- un-permute + transpose to (B, C, H, W) --------------------
__global__ __launch_bounds__(256) void k_out(const float* __restrict__ o,
                                             float* __restrict__ out) {
    __shared__ float tile[128][129];   // [c][ch]
    int b = blockIdx.x >> 7, r = blockIdx.x & 127;
    int t = threadIdx.x;
    int ctok = t >> 1, half = t & 1;
    long n = (((long)b * 32 + (r >> 2)) * 32 + (ctok >> 2)) * 16 + ((r & 3) * 4 + (ctok & 3));
    const float* src = o + n * 128 + half * 64;
#pragma unroll
    for (int jj = 0; jj < 16; ++jj) {
        float4 v = *(const float4*)&src[jj * 4];
        int base = half * 64 + jj * 4;
        tile[ctok][base + 0] = v.x;
        tile[ctok][base + 1] = v.y;
        tile[ctok][base + 2] = v.z;
        tile[ctok][base + 3] = v.w;
    }
    __syncthreads();
    int c = t & 127, hh = t >> 7;
    float* ob = out + ((long)b * 128 * 128 + r) * 128;
    for (int it = 0; it < 64; ++it) {
        int ch = it * 2 + hh;
        ob[(long)ch * 16384 + c] = tile[c][ch];
    }
}

extern "C" void kernel_launch(void* const* d_in, const int* in_sizes, int n_in,
                              void* d_out, int out_size, void* d_ws, size_t ws_size,
                              hipStream_t stream) {
    const float* x      = (const float*)d_in[0];
    const float* gamma1 = (const float*)d_in[1];
    const float* beta1  = (const float*)d_in[2];
    const float* sed_w  = (const float*)d_in[3];
    const float* w_proj = (const float*)d_in[4];
    const float* b_proj = (const float*)d_in[5];
    const float* gamma2 = (const float*)d_in[6];
    const float* beta2  = (const float*)d_in[7];
    const float* w1     = (const float*)d_in[8];
    const float* b1     = (const float*)d_in[9];
    const float* w2     = (const float*)d_in[10];
    const float* b2     = (const float*)d_in[11];

    char* ws = (char*)d_ws;
    bf16* At  = (bf16*)(ws + 0);          //  8,388,608  (2048x2048 bf16)
    bf16* wpT = (bf16*)(ws + 8388608);    //     32,768
    bf16* w1T = (bf16*)(ws + 8421376);    //    131,072
    bf16* w2T = (bf16*)(ws + 8552448);    //    131,072
    bf16* xt  = (bf16*)(ws + 8683520);    // 33,554,432  (131072 x 128 bf16)
    bf16* xn  = (bf16*)(ws + 42237952);   // 33,554,432
    bf16* g_  = (bf16*)(ws + 75792384);   // 33,554,432
    bf16* y2  = (bf16*)(ws + 109346816);  // 33,554,432
    bf16* mp  = (bf16*)(ws + 142901248);  // 33,554,432
    bf16* h   = (bf16*)(ws + 176455680);  // 33,554,432  (32768 x 512 bf16 chunk)
    float* op = (float*)(ws + 42237952);  // 67,108,864  aliases xn+g_ (both dead)

    hipLaunchKernelGGL(k_prep_w, dim3(576), dim3(256), 0, stream,
                       w_proj, w1, w2, wpT, w1T, w2T);
    hipLaunchKernelGGL(k_prep_A, dim3(256), dim3(256), 0, stream, sed_w, At);
    hipLaunchKernelGGL(k_ln1, dim3(1024), dim3(256), 0, stream,
                       x, gamma1, beta1, xt, xn);

    // SED: (8192 x 2048) @ (2048 x 2048)^T-stored, GELU, out bf16 token-major
    hipLaunchKernelGGL((k_gemm<1, 0, 0>), dim3(16, 64), dim3(256), 0, stream,
                       xn, At, (const float*)nullptr, (const bf16*)nullptr,
                       (void*)g_, 2048, 2048);
    // PROJ: (131072 x 128) @ (128 x 128) + b_proj + xt -> y2 bf16
    hipLaunchKernelGGL((k_gemm<0, 1, 0>), dim3(1, 1024), dim3(256), 0, stream,
                       g_, wpT, b_proj, xt, (void*)y2, 128, 128);
    hipLaunchKernelGGL(k_ln2, dim3(32768), dim3(256), 0, stream,
                       y2, gamma2, beta2, mp);
    // MLP in 4 row-chunks of 32768 tokens (h buffer reused)
    for (int ck = 0; ck < 4; ++ck) {
        const bf16* mc = mp + (long)ck * 32768 * 128;
        hipLaunchKernelGGL((k_gemm<1, 0, 0>), dim3(4, 256), dim3(256), 0, stream,
                           mc, w1T, b1, (const bf16*)nullptr, (void*)h, 128, 512);
        hipLaunchKernelGGL((k_gemm<0, 1, 1>), dim3(1, 256), dim3(256), 0, stream,
                           h, w2T, b2, y2 + (long)ck * 32768 * 128,
                           (void*)(op + (long)ck * 32768 * 128), 512, 128);
    }
    hipLaunchKernelGGL(k_out, dim3(1024), dim3(256), 0, stream, op, (float*)d_out);
}

// Round 2
// 477.381 us; speedup vs baseline: 1.1911x; 1.1911x over previous
//
#include <hip/hip_runtime.h>
#include <hip/hip_bf16.h>

#define DEVI __device__ __forceinline__

typedef __attribute__((ext_vector_type(8))) __bf16 bf16x8;
typedef __attribute__((ext_vector_type(4))) float f32x4;

using bf16 = __hip_bfloat16;

DEVI float bf2f(bf16 v) { return __bfloat162float(v); }
DEVI bf16 f2bf(float v) { return __float2bfloat16(v); }

DEVI float gelu_exact(float v) {
    return 0.5f * v * (1.0f + erff(v * 0.70710678118654752f));
}

DEVI void async16(void* lds, const void* g) {
    __builtin_amdgcn_global_load_lds(
        (const __attribute__((address_space(1))) void*)g,
        (__attribute__((address_space(3))) void*)lds, 16, 0, 0);
}

// sign of e_i * e_j in 16-dim Cayley-Dickson algebra (index is i^j)
DEVI int cd_sign(int i, int j) {
    int s = 1, n = 16;
    while (n > 1) {
        int h = n >> 1;
        int ih = (i >= h), jh = (j >= h);
        if (!ih && !jh) {
        } else if (!ih && jh) {
            int ni = j - h, nj = i;
            i = ni; j = nj;
        } else if (ih && !jh) {
            if (j != 0) s = -s;
            i = i - h;
        } else {
            int ni = j - h, nj = i - h;
            if (ni == 0) s = -s;
            i = ni; j = nj;
        }
        n = h;
    }
    return s;
}

// ---------------- prep: build A_T (2048x2048 bf16), row (k,d), col (i,c) ----
__global__ __launch_bounds__(256) void k_prep_A(const float* __restrict__ sed_w,
                                                bf16* __restrict__ At) {
    __shared__ float tile[128][129];
    int bi = blockIdx.x;  // 0..255
    int i = bi >> 4, k = bi & 15;
    int j = i ^ k;
    float s = (float)cd_sign(i, j);
    int t = threadIdx.x;
    int lo = t & 127, hi = t >> 7;
    const float* src = sed_w + j * 16384;
    for (int it = 0; it < 64; ++it) {
        int c = it * 2 + hi;
        tile[c][lo] = src[c * 128 + lo];
    }
    __syncthreads();
    for (int it = 0; it < 64; ++it) {
        int d = it * 2 + hi;
        At[(long)(k * 128 + d) * 2048 + i * 128 + lo] = f2bf(s * tile[lo][d]);
    }
}

// ---------------- prep: bf16 transposed weights -----------------------------
__global__ __launch_bounds__(256) void k_prep_w(const float* __restrict__ wp,
                                                const float* __restrict__ w1,
                                                const float* __restrict__ w2,
                                                bf16* __restrict__ wpT,
                                                bf16* __restrict__ w1T,
                                                bf16* __restrict__ w2T) {
    int idx = blockIdx.x * 256 + threadIdx.x;
    if (idx < 16384) {
        int d = idx >> 7, c = idx & 127;
        wpT[idx] = f2bf(wp[c * 128 + d]);              // wpT[d][c] = wp[c][d]
    } else if (idx < 16384 + 65536) {
        int e = idx - 16384;
        int o = e >> 7, c = e & 127;
        w1T[e] = f2bf(w1[c * 512 + o]);                // w1T[o][c] = w1[c][o]
    } else if (idx < 16384 + 131072) {
        int e = idx - 81920;
        int o = e >> 9, c = e & 511;
        w2T[e] = f2bf(w2[c * 128 + o]);                // w2T[o][c] = w2[c][o]
    }
}

// ---------------- LN1 + transpose to window-permuted token order ------------
__global__ __launch_bounds__(256) void k_ln1(const float* __restrict__ x,
                                             const float* __restrict__ g,
                                             const float* __restrict__ bta,
                                             bf16* __restrict__ xt,
                                             bf16* __restrict__ xn) {
    __shared__ float tile[128][128];   // [ch][c]
    __shared__ float ps[2][128], pss[2][128];
    int b = blockIdx.x >> 7, r = blockIdx.x & 127;
    int t = threadIdx.x, c = t & 127, half = t >> 7;
    const float* xb = x + ((long)b * 128 * 128 + r) * 128;
    for (int it = 0; it < 64; ++it) {
        int ch = it * 2 + half;
        tile[ch][c] = xb[(long)ch * 16384 + c];
    }
    __syncthreads();
    float s = 0.f, ss = 0.f;
    for (int ch = half * 64; ch < half * 64 + 64; ++ch) {
        float v = tile[ch][c];
        s += v; ss += v * v;
    }
    ps[half][c] = s; pss[half][c] = ss;
    __syncthreads();
    float S = ps[0][c] + ps[1][c], SS = pss[0][c] + pss[1][c];
    float mean = S * (1.f / 128.f);
    float var = SS * (1.f / 128.f) - mean * mean;
    float rstd = rsqrtf(var + 1e-5f);
    long n = (((long)b * 32 + (r >> 2)) * 32 + (c >> 2)) * 16 + ((r & 3) * 4 + (c & 3));
    bf16* xtr = xt + n * 128 + half * 64;
    bf16* xnr = xn + n * 128 + half * 64;
#pragma unroll
    for (int v8 = 0; v8 < 8; ++v8) {
        bf16x8 pt, pn;
#pragma unroll
        for (int e = 0; e < 8; ++e) {
            int ch = half * 64 + v8 * 8 + e;
            float v = tile[ch][c];
            pt[e] = (__bf16)v;
            pn[e] = (__bf16)((v - mean) * rstd * g[ch] + bta[ch]);
        }
        *(bf16x8*)&xtr[v8 * 8] = pt;
        *(bf16x8*)&xnr[v8 * 8] = pn;
    }
}

// ---------------- SED GEMM: 128x128 tile, BK=32, async16 staging ------------
__global__ __launch_bounds__(256) void k_gemm_sed(const bf16* __restrict__ A,
                                                  const bf16* __restrict__ Bt,
                                                  bf16* __restrict__ out) {
    const int K = 2048, N = 2048;
    __shared__ __align__(16) bf16 lA[128 * 32];
    __shared__ __align__(16) bf16 lB[128 * 32];
    int t = threadIdx.x;
    long bm = (long)blockIdx.y * 128;
    long bn = (long)blockIdx.x * 128;
    int lane = t & 63;
    int wm = ((t >> 7) & 1) * 64;
    int wn = ((t >> 6) & 1) * 64;
    int l15 = lane & 15, quad = lane >> 4;

    f32x4 acc[4][4] = {};

    int rowA = t >> 2;
    int seg = (t & 3) * 8;
    const bf16* gA = A + (bm + rowA) * (long)K + seg;
    const bf16* gB = Bt + (bn + rowA) * (long)K + seg;

    for (int k0 = 0; k0 < K; k0 += 32) {
        async16(&lA[t * 8], gA + k0);
        async16(&lA[2048 + t * 8], gA + (long)64 * K + k0);
        async16(&lB[t * 8], gB + k0);
        async16(&lB[2048 + t * 8], gB + (long)64 * K + k0);
        __syncthreads();
        bf16x8 af[4], bfr[4];
#pragma unroll
        for (int tm = 0; tm < 4; ++tm)
            af[tm] = *(const bf16x8*)&lA[(wm + tm * 16 + l15) * 32 + quad * 8];
#pragma unroll
        for (int tn = 0; tn < 4; ++tn)
            bfr[tn] = *(const bf16x8*)&lB[(wn + tn * 16 + l15) * 32 + quad * 8];
#pragma unroll
        for (int tm = 0; tm < 4; ++tm)
#pragma unroll
            for (int tn = 0; tn < 4; ++tn)
                acc[tm][tn] = __builtin_amdgcn_mfma_f32_16x16x32_bf16(
                    af[tm], bfr[tn], acc[tm][tn], 0, 0, 0);
        __syncthreads();
    }

#pragma unroll
    for (int tn = 0; tn < 4; ++tn) {
        long col = bn + wn + tn * 16 + l15;
#pragma unroll
        for (int tm = 0; tm < 4; ++tm) {
            long r0 = bm + wm + tm * 16 + quad * 4;
#pragma unroll
            for (int reg = 0; reg < 4; ++reg) {
                long r = r0 + reg;
                float v = gelu_exact(acc[tm][tn][reg]);
                out[r * N + col] = f2bf(v);
            }
        }
    }
}

// ---------------- fused tail: proj + res + LN2 + MLP1 + GELU + MLP2 + res ---
// one block = 128 tokens. A-operands for MLP from LDS in fragment-packed
// layout [k>>3][m][k&7]; B-operands (small weights) read direct from global.
__global__ __launch_bounds__(256, 2) void k_tail(
    const bf16* __restrict__ g_,   // SED out (131072 x 128)
    const bf16* __restrict__ wpT,  // (128 x 128): row d, col c
    const float* __restrict__ bproj,
    const bf16* __restrict__ xt,   // residual (131072 x 128)
    const float* __restrict__ gamma2, const float* __restrict__ beta2,
    const bf16* __restrict__ w1T,  // (512 x 128)
    const float* __restrict__ b1,
    const bf16* __restrict__ w2T,  // (128 x 512)
    const float* __restrict__ b2,
    bf16* __restrict__ op)         // (131072 x 128)
{
    __shared__ __align__(16) bf16 mpL[128 * 128];  // packed A-frag layout
    __shared__ __align__(16) bf16 hL[128 * 128];   // packed A-frag layout (chunk)
    float* stats = (float*)hL;  // overlay: sum[128][2], ss[128][2] = 2 KB

    int t = threadIdx.x;
    long bm = (long)blockIdx.x * 128;
    int lane = t & 63;
    int wm = ((t >> 7) & 1) * 64;
    int wn = ((t >> 6) & 1) * 64;
    int l15 = lane & 15, quad = lane >> 4;
    int half = wn >> 6;

    // ---- proj: y2 = g_tile @ wpT^T + bproj + xt (regs only) ----
    f32x4 acc1[4][4] = {};
#pragma unroll
    for (int k0 = 0; k0 < 128; k0 += 32) {
        bf16x8 af[4], bfr[4];
#pragma unroll
        for (int tm = 0; tm < 4; ++tm)
            af[tm] = *(const bf16x8*)&g_[(bm + wm + tm * 16 + l15) * 128 + k0 + quad * 8];
#pragma unroll
        for (int tn = 0; tn < 4; ++tn)
            bfr[tn] = *(const bf16x8*)&wpT[(wn + tn * 16 + l15) * 128 + k0 + quad * 8];
#pragma unroll
        for (int tm = 0; tm < 4; ++tm)
#pragma unroll
            for (int tn = 0; tn < 4; ++tn)
                acc1[tm][tn] = __builtin_amdgcn_mfma_f32_16x16x32_bf16(
                    af[tm], bfr[tn], acc1[tm][tn], 0, 0, 0);
    }
    float g2v[4], b2v[4];
#pragma unroll
    for (int tn = 0; tn < 4; ++tn) {
        int col = wn + tn * 16 + l15;
        float bv = bproj[col];
        g2v[tn] = gamma2[col];
        b2v[tn] = beta2[col];
#pragma unroll
        for (int tm = 0; tm < 4; ++tm) {
            int row = wm + tm * 16 + quad * 4;
#pragma unroll
            for (int reg = 0; reg < 4; ++reg)
                acc1[tm][tn][reg] += bv + bf2f(xt[(bm + row + reg) * 128 + col]);
        }
    }

    // ---- LN2 stats: per-row mean/var over 128 cols ----
#pragma unroll
    for (int tm = 0; tm < 4; ++tm) {
#pragma unroll
        for (int reg = 0; reg < 4; ++reg) {
            float rs = 0.f, rss = 0.f;
#pragma unroll
            for (int tn = 0; tn < 4; ++tn) {
                float v = acc1[tm][tn][reg];
                rs += v; rss += v * v;
            }
#pragma unroll
            for (int off = 1; off < 16; off <<= 1) {
                rs += __shfl_xor(rs, off);
                rss += __shfl_xor(rss, off);
            }
            if (l15 == 0) {
                int row = wm + tm * 16 + quad * 4 + reg;
                stats[row * 2 + half] = rs;
                stats[256 + row * 2 + half] = rss;
            }
        }
    }
    __syncthreads();

    // ---- mp = LN(y2)*gamma2+beta2, write to mpL packed ----
#pragma unroll
    for (int tm = 0; tm < 4; ++tm) {
#pragma unroll
        for (int reg = 0; reg < 4; ++reg) {
            int row = wm + tm * 16 + quad * 4 + reg;
            float S = stats[row * 2] + stats[row * 2 + 1];
            float SS = stats[256 + row * 2] + stats[256 + row * 2 + 1];
            float mean = S * (1.f / 128.f);
            float var = SS * (1.f / 128.f) - mean * mean;
            float rstd = rsqrtf(var + 1e-5f);
#pragma unroll
            for (int tn = 0; tn < 4; ++tn) {
                int col = wn + tn * 16 + l15;
                float v = (acc1[tm][tn][reg] - mean) * rstd * g2v[tn] + b2v[tn];
                ((unsigned short*)mpL)[((col >> 3) * 128 + row) * 8 + (col & 7)] =
                    __bfloat16_as_ushort(f2bf(v));
            }
        }
    }
    __syncthreads();

    // ---- MLP: 4 hidden chunks of 128; h stays in LDS ----
    f32x4 acc2[4][4] = {};
    for (int oh = 0; oh < 4; ++oh) {
        f32x4 acch[4][4] = {};
#pragma unroll
        for (int k0 = 0; k0 < 128; k0 += 32) {
            bf16x8 af[4], bfr[4];
#pragma unroll
            for (int tm = 0; tm < 4; ++tm)
                af[tm] = *(const bf16x8*)&mpL[((k0 >> 3) + quad) * 1024 +
                                              (wm + tm * 16 + l15) * 8];
#pragma unroll
            for (int tn = 0; tn < 4; ++tn)
                bfr[tn] = *(const bf16x8*)&w1T[(oh * 128 + wn + tn * 16 + l15) * 128 +
                                               k0 + quad * 8];
#pragma unroll
            for (int tm = 0; tm < 4; ++tm)
#pragma unroll
                for (int tn = 0; tn < 4; ++tn)
                    acch[tm][tn] = __builtin_amdgcn_mfma_f32_16x16x32_bf16(
                        af[tm], bfr[tn], acch[tm][tn], 0, 0, 0);
        }
        // GELU epilogue -> hL packed
#pragma unroll
        for (int tn = 0; tn < 4; ++tn) {
            int ncol = wn + tn * 16 + l15;
            float bh = b1[oh * 128 + ncol];
#pragma unroll
            for (int tm = 0; tm < 4; ++tm) {
#pragma unroll
                for (int reg = 0; reg < 4; ++reg) {
                    int row = wm + tm * 16 + quad * 4 + reg;
                    float v = gelu_exact(acch[tm][tn][reg] + bh);
                    ((unsigned short*)hL)[((ncol >> 3) * 128 + row) * 8 + (ncol & 7)] =
                        __bfloat16_as_ushort(f2bf(v));
                }
            }
        }
        __syncthreads();
        // MLP2 partial: acc2 += h_chunk @ w2T[:, oh*128 : oh*128+128]^T
#pragma unroll
        for (int k0 = 0; k0 < 128; k0 += 32) {
            bf16x8 af[4], bfr[4];
#pragma unroll
            for (int tm = 0; tm < 4; ++tm)
                af[tm] = *(const bf16x8*)&hL[((k0 >> 3) + quad) * 1024 +
                                             (wm + tm * 16 + l15) * 8];
#pragma unroll
            for (int tn = 0; tn < 4; ++tn)
                bfr[tn] = *(const bf16x8*)&w2T[(wn + tn * 16 + l15) * 512 +
                                               oh * 128 + k0 + quad * 8];
#pragma unroll
            for (int tm = 0; tm < 4; ++tm)
#pragma unroll
                for (int tn = 0; tn < 4; ++tn)
                    acc2[tm][tn] = __builtin_amdgcn_mfma_f32_16x16x32_bf16(
                        af[tm], bfr[tn], acc2[tm][tn], 0, 0, 0);
        }
        __syncthreads();  // protect hL before next chunk overwrites
    }

    // ---- final: op = y2 + mlp2 + b2 ----
#pragma unroll
    for (int tn = 0; tn < 4; ++tn) {
        int col = wn + tn * 16 + l15;
        float bv = b2[col];
#pragma unroll
        for (int tm = 0; tm < 4; ++tm) {
            int row = wm + tm * 16 + quad * 4;
#pragma unroll
            for (int reg = 0; reg < 4; ++reg) {
                float v = acc1[tm][tn][reg] + acc2[tm][tn][reg] + bv;
                op[(bm + row + reg) * 128 + col] = f2bf(v);
            }
        }
    }
}

// ---------------- un-permute + transpose to (B, C, H, W) --------------------
__global__ __launch_bounds__(256) void k_out(const bf16* __restrict__ o,
                                             float* __restrict__ out) {
    __shared__ float tile[128][129];   // [c][ch]
    int b = blockIdx.x >> 7, r = blockIdx.x & 127;
    int t = threadIdx.x;
    int ctok = t >> 1, half = t & 1;
    long n = (((long)b * 32 + (r >> 2)) * 32 + (ctok >> 2)) * 16 + ((r & 3) * 4 + (ctok & 3));
    const bf16* src = o + n * 128 + half * 64;
#pragma unroll
    for (int jj = 0; jj < 8; ++jj) {
        bf16x8 v = *(const bf16x8*)&src[jj * 8];
        int base = half * 64 + jj * 8;
#pragma unroll
        for (int e = 0; e < 8; ++e)
            tile[ctok][base + e] = (float)v[e];
    }
    __syncthreads();
    int c = t & 127, hh = t >> 7;
    float* ob = out + ((long)b * 128 * 128 + r) * 128;
    for (int it = 0; it < 64; ++it) {
        int ch = it * 2 + hh;
        ob[(long)ch * 16384 + c] = tile[c][ch];
    }
}

extern "C" void kernel_launch(void* const* d_in, const int* in_sizes, int n_in,
                              void* d_out, int out_size, void* d_ws, size_t ws_size,
                              hipStream_t stream) {
    const float* x      = (const float*)d_in[0];
    const float* gamma1 = (const float*)d_in[1];
    const float* beta1  = (const float*)d_in[2];
    const float* sed_w  = (const float*)d_in[3];
    const float* w_proj = (const float*)d_in[4];
    const float* b_proj = (const float*)d_in[5];
    const float* gamma2 = (const float*)d_in[6];
    const float* beta2  = (const float*)d_in[7];
    const float* w1     = (const float*)d_in[8];
    const float* b1     = (const float*)d_in[9];
    const float* w2     = (const float*)d_in[10];
    const float* b2     = (const float*)d_in[11];

    char* ws = (char*)d_ws;
    bf16* At  = (bf16*)(ws + 0);           //  8,388,608
    bf16* wpT = (bf16*)(ws + 8388608);     //     32,768
    bf16* w1T = (bf16*)(ws + 8421376);     //    131,072
    bf16* w2T = (bf16*)(ws + 8552448);     //    131,072
    bf16* xt  = (bf16*)(ws + 8683520);     // 33,554,432
    bf16* xn  = (bf16*)(ws + 42237952);    // 33,554,432
    bf16* g_  = (bf16*)(ws + 75792384);    // 33,554,432
    bf16* op  = (bf16*)(ws + 109346816);   // 33,554,432

    hipLaunchKernelGGL(k_prep_w, dim3(576), dim3(256), 0, stream,
                       w_proj, w1, w2, wpT, w1T, w2T);
    hipLaunchKernelGGL(k_prep_A, dim3(256), dim3(256), 0, stream, sed_w, At);
    hipLaunchKernelGGL(k_ln1, dim3(1024), dim3(256), 0, stream,
                       x, gamma1, beta1, xt, xn);
    // SED: (8192 windows x 2048) @ (2048 x 2048), GELU, bf16 token-major
    hipLaunchKernelGGL(k_gemm_sed, dim3(16, 64), dim3(256), 0, stream,
                       xn, At, g_);
    // fused tail: proj + residual + LN2 + MLP (h in LDS) + residual
    hipLaunchKernelGGL(k_tail, dim3(1024), dim3(256), 0, stream,
                       g_, wpT, b_proj, xt, gamma2, beta2,
                       w1T, b1, w2T, b2, op);
    hipLaunchKernelGGL(k_out, dim3(1024), dim3(256), 0, stream, op, (float*)d_out);
}

// Round 3
// 427.921 us; speedup vs baseline: 1.3288x; 1.1156x over previous
//
#include <hip/hip_runtime.h>
#include <hip/hip_bf16.h>

#define DEVI __device__ __forceinline__

typedef __attribute__((ext_vector_type(8))) __bf16 bf16x8;
typedef __attribute__((ext_vector_type(4))) __bf16 bf16x4;
typedef __attribute__((ext_vector_type(4))) float f32x4;

using bf16 = __hip_bfloat16;

DEVI float bf2f(bf16 v) { return __bfloat162float(v); }
DEVI bf16 f2bf(float v) { return __float2bfloat16(v); }

DEVI float gelu_exact(float v) {
    return 0.5f * v * (1.0f + erff(v * 0.70710678118654752f));
}

DEVI void async16(void* lds, const void* g) {
    __builtin_amdgcn_global_load_lds(
        (const __attribute__((address_space(1))) void*)g,
        (__attribute__((address_space(3))) void*)lds, 16, 0, 0);
}

// sign of e_i * e_j in 16-dim Cayley-Dickson algebra (index is i^j)
DEVI int cd_sign(int i, int j) {
    int s = 1, n = 16;
    while (n > 1) {
        int h = n >> 1;
        int ih = (i >= h), jh = (j >= h);
        if (!ih && !jh) {
        } else if (!ih && jh) {
            int ni = j - h, nj = i;
            i = ni; j = nj;
        } else if (ih && !jh) {
            if (j != 0) s = -s;
            i = i - h;
        } else {
            int ni = j - h, nj = i - h;
            if (ni == 0) s = -s;
            i = ni; j = nj;
        }
        n = h;
    }
    return s;
}

// ---------------- prep: build A_T (2048x2048 bf16), row (k,d), col (i,c) ----
__global__ __launch_bounds__(256) void k_prep_A(const float* __restrict__ sed_w,
                                                bf16* __restrict__ At) {
    __shared__ float tile[128][129];
    int bi = blockIdx.x;  // 0..255
    int i = bi >> 4, k = bi & 15;
    int j = i ^ k;
    float s = (float)cd_sign(i, j);
    int t = threadIdx.x;
    int lo = t & 127, hi = t >> 7;
    const float* src = sed_w + j * 16384;
    for (int it = 0; it < 64; ++it) {
        int c = it * 2 + hi;
        tile[c][lo] = src[c * 128 + lo];
    }
    __syncthreads();
    for (int it = 0; it < 64; ++it) {
        int d = it * 2 + hi;
        At[(long)(k * 128 + d) * 2048 + i * 128 + lo] = f2bf(s * tile[lo][d]);
    }
}

// ---------------- prep: bf16 transposed weights -----------------------------
__global__ __launch_bounds__(256) void k_prep_w(const float* __restrict__ wp,
                                                const float* __restrict__ w1,
                                                const float* __restrict__ w2,
                                                bf16* __restrict__ wpT,
                                                bf16* __restrict__ w1T,
                                                bf16* __restrict__ w2T) {
    int idx = blockIdx.x * 256 + threadIdx.x;
    if (idx < 16384) {
        int d = idx >> 7, c = idx & 127;
        wpT[idx] = f2bf(wp[c * 128 + d]);              // wpT[d][c] = wp[c][d]
    } else if (idx < 16384 + 65536) {
        int e = idx - 16384;
        int o = e >> 7, c = e & 127;
        w1T[e] = f2bf(w1[c * 512 + o]);                // w1T[o][c] = w1[c][o]
    } else if (idx < 16384 + 131072) {
        int e = idx - 81920;
        int o = e >> 9, c = e & 511;
        w2T[e] = f2bf(w2[c * 128 + o]);                // w2T[o][c] = w2[c][o]
    }
}

// ---------------- LN1 + transpose to window-permuted token order ------------
__global__ __launch_bounds__(256) void k_ln1(const float* __restrict__ x,
                                             const float* __restrict__ g,
                                             const float* __restrict__ bta,
                                             bf16* __restrict__ xt,
                                             bf16* __restrict__ xn) {
    __shared__ float tile[128][128];   // [ch][c]
    __shared__ float ps[2][128], pss[2][128];
    int b = blockIdx.x >> 7, r = blockIdx.x & 127;
    int t = threadIdx.x, c = t & 127, half = t >> 7;
    const float* xb = x + ((long)b * 128 * 128 + r) * 128;
    for (int it = 0; it < 64; ++it) {
        int ch = it * 2 + half;
        tile[ch][c] = xb[(long)ch * 16384 + c];
    }
    __syncthreads();
    float s = 0.f, ss = 0.f;
    for (int ch = half * 64; ch < half * 64 + 64; ++ch) {
        float v = tile[ch][c];
        s += v; ss += v * v;
    }
    ps[half][c] = s; pss[half][c] = ss;
    __syncthreads();
    float S = ps[0][c] + ps[1][c], SS = pss[0][c] + pss[1][c];
    float mean = S * (1.f / 128.f);
    float var = SS * (1.f / 128.f) - mean * mean;
    float rstd = rsqrtf(var + 1e-5f);
    long n = (((long)b * 32 + (r >> 2)) * 32 + (c >> 2)) * 16 + ((r & 3) * 4 + (c & 3));
    bf16* xtr = xt + n * 128 + half * 64;
    bf16* xnr = xn + n * 128 + half * 64;
#pragma unroll
    for (int v8 = 0; v8 < 8; ++v8) {
        bf16x8 pt, pn;
#pragma unroll
        for (int e = 0; e < 8; ++e) {
            int ch = half * 64 + v8 * 8 + e;
            float v = tile[ch][c];
            pt[e] = (__bf16)v;
            pn[e] = (__bf16)((v - mean) * rstd * g[ch] + bta[ch]);
        }
        *(bf16x8*)&xtr[v8 * 8] = pt;
        *(bf16x8*)&xnr[v8 * 8] = pn;
    }
}

// ---------------- SED GEMM (transposed): D[kd][win] = At @ xn^T -------------
// M = kd (2048, blockIdx.y), N = windows (8192, blockIdx.x). Since lane regs
// hold 4 consecutive M-rows = 4 consecutive kd (contiguous in g_), pack bf16x4
// -> LDS tile [win][kd] -> fully coalesced b128 stores.
__global__ __launch_bounds__(256) void k_gemm_sed(const bf16* __restrict__ At,
                                                  const bf16* __restrict__ xn,
                                                  bf16* __restrict__ g_) {
    const int K = 2048;
    __shared__ __align__(16) bf16 lA[128 * 32];
    __shared__ __align__(16) bf16 lB[128 * 32];
    __shared__ __align__(16) bf16 sOut[128 * 136];
    int t = threadIdx.x;
    long bm = (long)blockIdx.y * 128;   // kd base
    long bn = (long)blockIdx.x * 128;   // window base
    int lane = t & 63;
    int wm = ((t >> 7) & 1) * 64;
    int wn = ((t >> 6) & 1) * 64;
    int l15 = lane & 15, quad = lane >> 4;

    f32x4 acc[4][4] = {};

    int rowA = t >> 2;
    int seg = (t & 3) * 8;
    const bf16* gA = At + (bm + rowA) * (long)K + seg;
    const bf16* gB = xn + (bn + rowA) * (long)K + seg;

    for (int k0 = 0; k0 < K; k0 += 32) {
        async16(&lA[t * 8], gA + k0);
        async16(&lA[2048 + t * 8], gA + (long)64 * K + k0);
        async16(&lB[t * 8], gB + k0);
        async16(&lB[2048 + t * 8], gB + (long)64 * K + k0);
        __syncthreads();
        bf16x8 af[4], bfr[4];
#pragma unroll
        for (int tm = 0; tm < 4; ++tm)
            af[tm] = *(const bf16x8*)&lA[(wm + tm * 16 + l15) * 32 + quad * 8];
#pragma unroll
        for (int tn = 0; tn < 4; ++tn)
            bfr[tn] = *(const bf16x8*)&lB[(wn + tn * 16 + l15) * 32 + quad * 8];
#pragma unroll
        for (int tm = 0; tm < 4; ++tm)
#pragma unroll
            for (int tn = 0; tn < 4; ++tn)
                acc[tm][tn] = __builtin_amdgcn_mfma_f32_16x16x32_bf16(
                    af[tm], bfr[tn], acc[tm][tn], 0, 0, 0);
        __syncthreads();
    }

    // epilogue: GELU, pack 4 consecutive kd -> LDS [win][kd] (pitch 136)
#pragma unroll
    for (int tn = 0; tn < 4; ++tn) {
        int win = wn + tn * 16 + l15;
#pragma unroll
        for (int tm = 0; tm < 4; ++tm) {
            int kd = wm + tm * 16 + quad * 4;
            bf16x4 p;
#pragma unroll
            for (int reg = 0; reg < 4; ++reg)
                p[reg] = (__bf16)gelu_exact(acc[tm][tn][reg]);
            *(bf16x4*)&sOut[win * 136 + kd] = p;
        }
    }
    __syncthreads();
    // coalesced store: each thread moves 16B segments
#pragma unroll
    for (int it = 0; it < 8; ++it) {
        int id = it * 256 + t;
        int win = id >> 4, sg = id & 15;
        bf16x8 v = *(const bf16x8*)&sOut[win * 136 + sg * 8];
        *(bf16x8*)&g_[(bn + win) * 2048 + bm + sg * 8] = v;
    }
}

// ---------------- fused tail (transposed): channels x tokens ----------------
// proj + bias + residual + LN2 + MLP1 + GELU + MLP2 + bias + residual
// + un-permute + fp32 output store. One block = 128 tokens (8 windows).
__global__ __launch_bounds__(256, 2) void k_tail(
    const bf16* __restrict__ g_,   // (131072 x 128) token-major
    const bf16* __restrict__ wpT,  // (128 x 128): row d, col c
    const float* __restrict__ bproj,
    const bf16* __restrict__ xt,   // residual (131072 x 128)
    const float* __restrict__ gamma2, const float* __restrict__ beta2,
    const bf16* __restrict__ w1T,  // (512 x 128)
    const float* __restrict__ b1,
    const bf16* __restrict__ w2T,  // (128 x 512)
    const float* __restrict__ b2,
    float* __restrict__ out)       // (8,128,128,128) fp32
{
    __shared__ __align__(16) char buf[69632];
    bf16* mpT = (bf16*)buf;                 // [token][channel] pitch 136
    bf16* hT = (bf16*)(buf + 34816);        // [token][hidden_c] pitch 136
    float* outF = (float*)buf;              // [channel][token] pitch 132 (overlay)
    __shared__ float stats[512];            // s[128][2], ss at +256

    int t = threadIdx.x;
    long tb = (long)blockIdx.x * 128;
    int lane = t & 63;
    int wm = ((t >> 7) & 1) * 64;
    int wn = ((t >> 6) & 1) * 64;
    int l15 = lane & 15, quad = lane >> 4;
    int half = wm >> 6;

    int tok[4];
#pragma unroll
    for (int tn = 0; tn < 4; ++tn) tok[tn] = wn + tn * 16 + l15;

    // ---- proj (transposed): acc1[d][tok] = wpT @ g_^T ----
    f32x4 acc1[4][4] = {};
#pragma unroll
    for (int k0 = 0; k0 < 128; k0 += 32) {
        bf16x8 af[4], bfr[4];
#pragma unroll
        for (int tm = 0; tm < 4; ++tm)
            af[tm] = *(const bf16x8*)&wpT[(wm + tm * 16 + l15) * 128 + k0 + quad * 8];
#pragma unroll
        for (int tn = 0; tn < 4; ++tn)
            bfr[tn] = *(const bf16x8*)&g_[(tb + tok[tn]) * 128 + k0 + quad * 8];
#pragma unroll
        for (int tm = 0; tm < 4; ++tm)
#pragma unroll
            for (int tn = 0; tn < 4; ++tn)
                acc1[tm][tn] = __builtin_amdgcn_mfma_f32_16x16x32_bf16(
                    af[tm], bfr[tn], acc1[tm][tn], 0, 0, 0);
    }

    // ---- + bproj[channel] + xt[token][channel] ----
#pragma unroll
    for (int tm = 0; tm < 4; ++tm) {
        int c0 = wm + tm * 16 + quad * 4;
        float4 bp = *(const float4*)&bproj[c0];
#pragma unroll
        for (int tn = 0; tn < 4; ++tn) {
            bf16x4 xv = *(const bf16x4*)&xt[(tb + tok[tn]) * 128 + c0];
#pragma unroll
            for (int reg = 0; reg < 4; ++reg)
                acc1[tm][tn][reg] += ((const float*)&bp)[reg] + (float)xv[reg];
        }
    }

    // ---- LN2 stats: per-token sum over channels (rows) ----
#pragma unroll
    for (int tn = 0; tn < 4; ++tn) {
        float s = 0.f, ss = 0.f;
#pragma unroll
        for (int tm = 0; tm < 4; ++tm)
#pragma unroll
            for (int reg = 0; reg < 4; ++reg) {
                float v = acc1[tm][tn][reg];
                s += v; ss += v * v;
            }
        s += __shfl_xor(s, 16); ss += __shfl_xor(ss, 16);
        s += __shfl_xor(s, 32); ss += __shfl_xor(ss, 32);
        if (quad == 0) {
            stats[tok[tn] * 2 + half] = s;
            stats[256 + tok[tn] * 2 + half] = ss;
        }
    }
    __syncthreads();

    // ---- LN apply -> mpT [token][channel] (b64 packed writes) ----
    float mean[4], rstd[4];
#pragma unroll
    for (int tn = 0; tn < 4; ++tn) {
        float S = stats[tok[tn] * 2] + stats[tok[tn] * 2 + 1];
        float SS = stats[256 + tok[tn] * 2] + stats[256 + tok[tn] * 2 + 1];
        mean[tn] = S * (1.f / 128.f);
        float var = SS * (1.f / 128.f) - mean[tn] * mean[tn];
        rstd[tn] = rsqrtf(var + 1e-5f);
    }
#pragma unroll
    for (int tm = 0; tm < 4; ++tm) {
        int c0 = wm + tm * 16 + quad * 4;
        float4 gv = *(const float4*)&gamma2[c0];
        float4 bv = *(const float4*)&beta2[c0];
#pragma unroll
        for (int tn = 0; tn < 4; ++tn) {
            bf16x4 p;
#pragma unroll
            for (int reg = 0; reg < 4; ++reg)
                p[reg] = (__bf16)((acc1[tm][tn][reg] - mean[tn]) * rstd[tn] *
                                      ((const float*)&gv)[reg] +
                                  ((const float*)&bv)[reg]);
            *(bf16x4*)&mpT[tok[tn] * 136 + c0] = p;
        }
    }
    __syncthreads();

    // ---- MLP: 4 hidden chunks of 128; h stays in LDS ----
    f32x4 acc2[4][4] = {};
    for (int oh = 0; oh < 4; ++oh) {
        f32x4 acch[4][4] = {};
#pragma unroll
        for (int k0 = 0; k0 < 128; k0 += 32) {
            bf16x8 af[4], bfr[4];
#pragma unroll
            for (int tm = 0; tm < 4; ++tm)
                af[tm] = *(const bf16x8*)&w1T[(oh * 128 + wm + tm * 16 + l15) * 128 +
                                              k0 + quad * 8];
#pragma unroll
            for (int tn = 0; tn < 4; ++tn)
                bfr[tn] = *(const bf16x8*)&mpT[tok[tn] * 136 + k0 + quad * 8];
#pragma unroll
            for (int tm = 0; tm < 4; ++tm)
#pragma unroll
                for (int tn = 0; tn < 4; ++tn)
                    acch[tm][tn] = __builtin_amdgcn_mfma_f32_16x16x32_bf16(
                        af[tm], bfr[tn], acch[tm][tn], 0, 0, 0);
        }
        // GELU + b1 -> hT [token][hidden_c] (b64 packed)
#pragma unroll
        for (int tm = 0; tm < 4; ++tm) {
            int hc0 = wm + tm * 16 + quad * 4;
            float4 bh = *(const float4*)&b1[oh * 128 + hc0];
#pragma unroll
            for (int tn = 0; tn < 4; ++tn) {
                bf16x4 p;
#pragma unroll
                for (int reg = 0; reg < 4; ++reg)
                    p[reg] = (__bf16)gelu_exact(acch[tm][tn][reg] +
                                                ((const float*)&bh)[reg]);
                *(bf16x4*)&hT[tok[tn] * 136 + hc0] = p;
            }
        }
        __syncthreads();
        // MLP2 partial: acc2 += w2T-chunk @ hT^T
#pragma unroll
        for (int k0 = 0; k0 < 128; k0 += 32) {
            bf16x8 af[4], bfr[4];
#pragma unroll
            for (int tm = 0; tm < 4; ++tm)
                af[tm] = *(const bf16x8*)&w2T[(wm + tm * 16 + l15) * 512 +
                                              oh * 128 + k0 + quad * 8];
#pragma unroll
            for (int tn = 0; tn < 4; ++tn)
                bfr[tn] = *(const bf16x8*)&hT[tok[tn] * 136 + k0 + quad * 8];
#pragma unroll
            for (int tm = 0; tm < 4; ++tm)
#pragma unroll
                for (int tn = 0; tn < 4; ++tn)
                    acc2[tm][tn] = __builtin_amdgcn_mfma_f32_16x16x32_bf16(
                        af[tm], bfr[tn], acc2[tm][tn], 0, 0, 0);
        }
        __syncthreads();
    }

    // ---- final: outF[c][tk] = acc1 + acc2 + b2[c], fp32 (overlay mpT/hT) ----
#pragma unroll
    for (int tm = 0; tm < 4; ++tm) {
        int c0 = wm + tm * 16 + quad * 4;
        float4 bv = *(const float4*)&b2[c0];
#pragma unroll
        for (int tn = 0; tn < 4; ++tn) {
#pragma unroll
            for (int reg = 0; reg < 4; ++reg)
                outF[(c0 + reg) * 132 + tok[tn]] =
                    acc1[tm][tn][reg] + acc2[tm][tn][reg] + ((const float*)&bv)[reg];
        }
    }
    __syncthreads();

    // ---- un-permute + coalesced fp32 store ----
    // block tokens = 8 consecutive windows: decode spatial position
    long win0 = tb >> 4;
    int b = (int)(win0 >> 10);
    int hq = (int)(win0 >> 5) & 31;
    int wq0 = (int)win0 & 31;
#pragma unroll
    for (int it = 0; it < 16; ++it) {
        int id = it * 256 + t;
        int c = id >> 5, rem = id & 31;
        int rr = rem >> 3, wqo = rem & 7;
        f32x4 v = *(const f32x4*)&outF[c * 132 + wqo * 16 + rr * 4];
        long addr = (((long)b * 128 + c) * 128 + hq * 4 + rr) * 128 + (wq0 + wqo) * 4;
        *(f32x4*)&out[addr] = v;
    }
}

extern "C" void kernel_launch(void* const* d_in, const int* in_sizes, int n_in,
                              void* d_out, int out_size, void* d_ws, size_t ws_size,
                              hipStream_t stream) {
    const float* x      = (const float*)d_in[0];
    const float* gamma1 = (const float*)d_in[1];
    const float* beta1  = (const float*)d_in[2];
    const float* sed_w  = (const float*)d_in[3];
    const float* w_proj = (const float*)d_in[4];
    const float* b_proj = (const float*)d_in[5];
    const float* gamma2 = (const float*)d_in[6];
    const float* beta2  = (const float*)d_in[7];
    const float* w1     = (const float*)d_in[8];
    const float* b1     = (const float*)d_in[9];
    const float* w2     = (const float*)d_in[10];
    const float* b2     = (const float*)d_in[11];

    char* ws = (char*)d_ws;
    bf16* At  = (bf16*)(ws + 0);           //  8,388,608
    bf16* wpT = (bf16*)(ws + 8388608);     //     32,768
    bf16* w1T = (bf16*)(ws + 8421376);     //    131,072
    bf16* w2T = (bf16*)(ws + 8552448);     //    131,072
    bf16* xt  = (bf16*)(ws + 8683520);     // 33,554,432
    bf16* xn  = (bf16*)(ws + 42237952);    // 33,554,432
    bf16* g_  = (bf16*)(ws + 75792384);    // 33,554,432

    hipLaunchKernelGGL(k_prep_w, dim3(576), dim3(256), 0, stream,
                       w_proj, w1, w2, wpT, w1T, w2T);
    hipLaunchKernelGGL(k_prep_A, dim3(256), dim3(256), 0, stream, sed_w, At);
    hipLaunchKernelGGL(k_ln1, dim3(1024), dim3(256), 0, stream,
                       x, gamma1, beta1, xt, xn);
    // SED (transposed): D[kd][win]; grid x = 8192/128 windows, y = 2048/128 kd
    hipLaunchKernelGGL(k_gemm_sed, dim3(64, 16), dim3(256), 0, stream,
                       At, xn, g_);
    // fused tail: proj + res + LN2 + MLP + res + un-permute + fp32 out
    hipLaunchKernelGGL(k_tail, dim3(1024), dim3(256), 0, stream,
                       g_, wpT, b_proj, xt, gamma2, beta2,
                       w1T, b1, w2T, b2, (float*)d_out);
}

// Round 4
// 400.403 us; speedup vs baseline: 1.4201x; 1.0687x over previous
//
#include <hip/hip_runtime.h>
#include <hip/hip_bf16.h>

#define DEVI __device__ __forceinline__

typedef __attribute__((ext_vector_type(8))) __bf16 bf16x8;
typedef __attribute__((ext_vector_type(4))) __bf16 bf16x4;
typedef __attribute__((ext_vector_type(4))) float f32x4;

using bf16 = __hip_bfloat16;

DEVI float bf2f(bf16 v) { return __bfloat162float(v); }
DEVI bf16 f2bf(float v) { return __float2bfloat16(v); }

// tanh-form GELU: v * sigmoid(2*sqrt(2/pi)*(v + 0.044715 v^3))
// = v - v / (exp2(v*(c1 + c2*v^2)) + 1);  c1 = 2*log2(e)*sqrt(2/pi)
// max |diff vs exact erf-GELU| ~ 3e-3, far under bf16 epilogue noise.
DEVI float gelu_fast(float v) {
    float t = v * (2.30220777f + 0.10294322f * v * v);
    float e = __builtin_amdgcn_exp2f(t);
    return v - v * __builtin_amdgcn_rcpf(e + 1.0f);
}

DEVI void async16(void* lds, const void* g) {
    __builtin_amdgcn_global_load_lds(
        (const __attribute__((address_space(1))) void*)g,
        (__attribute__((address_space(3))) void*)lds, 16, 0, 0);
}

// sign of e_i * e_j in 16-dim Cayley-Dickson algebra (index is i^j)
DEVI int cd_sign(int i, int j) {
    int s = 1, n = 16;
    while (n > 1) {
        int h = n >> 1;
        int ih = (i >= h), jh = (j >= h);
        if (!ih && !jh) {
        } else if (!ih && jh) {
            int ni = j - h, nj = i;
            i = ni; j = nj;
        } else if (ih && !jh) {
            if (j != 0) s = -s;
            i = i - h;
        } else {
            int ni = j - h, nj = i - h;
            if (ni == 0) s = -s;
            i = ni; j = nj;
        }
        n = h;
    }
    return s;
}

// ---------------- prep: build A_T (2048x2048 bf16), row (k,d), col (i,c) ----
__global__ __launch_bounds__(256) void k_prep_A(const float* __restrict__ sed_w,
                                                bf16* __restrict__ At) {
    __shared__ float tile[128][129];
    int bi = blockIdx.x;  // 0..255
    int i = bi >> 4, k = bi & 15;
    int j = i ^ k;
    float s = (float)cd_sign(i, j);
    int t = threadIdx.x;
    int lo = t & 127, hi = t >> 7;
    const float* src = sed_w + j * 16384;
    for (int it = 0; it < 64; ++it) {
        int c = it * 2 + hi;
        tile[c][lo] = src[c * 128 + lo];
    }
    __syncthreads();
    for (int it = 0; it < 64; ++it) {
        int d = it * 2 + hi;
        At[(long)(k * 128 + d) * 2048 + i * 128 + lo] = f2bf(s * tile[lo][d]);
    }
}

// ---------------- prep: bf16 transposed weights -----------------------------
__global__ __launch_bounds__(256) void k_prep_w(const float* __restrict__ wp,
                                                const float* __restrict__ w1,
                                                const float* __restrict__ w2,
                                                bf16* __restrict__ wpT,
                                                bf16* __restrict__ w1T,
                                                bf16* __restrict__ w2T) {
    int idx = blockIdx.x * 256 + threadIdx.x;
    if (idx < 16384) {
        int d = idx >> 7, c = idx & 127;
        wpT[idx] = f2bf(wp[c * 128 + d]);              // wpT[d][c] = wp[c][d]
    } else if (idx < 16384 + 65536) {
        int e = idx - 16384;
        int o = e >> 7, c = e & 127;
        w1T[e] = f2bf(w1[c * 512 + o]);                // w1T[o][c] = w1[c][o]
    } else if (idx < 16384 + 131072) {
        int e = idx - 81920;
        int o = e >> 9, c = e & 511;
        w2T[e] = f2bf(w2[c * 128 + o]);                // w2T[o][c] = w2[c][o]
    }
}

// ---------------- LN1 + transpose to window-permuted token order ------------
__global__ __launch_bounds__(256) void k_ln1(const float* __restrict__ x,
                                             const float* __restrict__ g,
                                             const float* __restrict__ bta,
                                             bf16* __restrict__ xt,
                                             bf16* __restrict__ xn) {
    __shared__ float tile[128][128];   // [ch][c]
    __shared__ float ps[2][128], pss[2][128];
    int b = blockIdx.x >> 7, r = blockIdx.x & 127;
    int t = threadIdx.x, c = t & 127, half = t >> 7;
    const float* xb = x + ((long)b * 128 * 128 + r) * 128;
    for (int it = 0; it < 64; ++it) {
        int ch = it * 2 + half;
        tile[ch][c] = xb[(long)ch * 16384 + c];
    }
    __syncthreads();
    float s = 0.f, ss = 0.f;
    for (int ch = half * 64; ch < half * 64 + 64; ++ch) {
        float v = tile[ch][c];
        s += v; ss += v * v;
    }
    ps[half][c] = s; pss[half][c] = ss;
    __syncthreads();
    float S = ps[0][c] + ps[1][c], SS = pss[0][c] + pss[1][c];
    float mean = S * (1.f / 128.f);
    float var = SS * (1.f / 128.f) - mean * mean;
    float rstd = rsqrtf(var + 1e-5f);
    long n = (((long)b * 32 + (r >> 2)) * 32 + (c >> 2)) * 16 + ((r & 3) * 4 + (c & 3));
    bf16* xtr = xt + n * 128 + half * 64;
    bf16* xnr = xn + n * 128 + half * 64;
#pragma unroll
    for (int v8 = 0; v8 < 8; ++v8) {
        bf16x8 pt, pn;
#pragma unroll
        for (int e = 0; e < 8; ++e) {
            int ch = half * 64 + v8 * 8 + e;
            float v = tile[ch][c];
            pt[e] = (__bf16)v;
            pn[e] = (__bf16)((v - mean) * rstd * g[ch] + bta[ch]);
        }
        *(bf16x8*)&xtr[v8 * 8] = pt;
        *(bf16x8*)&xnr[v8 * 8] = pn;
    }
}

// ---------------- SED GEMM (transposed): D[kd][win] = At @ xn^T -------------
// sOut overlays lA/lB (dead after K-loop) -> LDS 34816 B -> 4 blocks/CU.
__global__ __launch_bounds__(256, 4) void k_gemm_sed(const bf16* __restrict__ At,
                                                     const bf16* __restrict__ xn,
                                                     bf16* __restrict__ g_) {
    const int K = 2048;
    __shared__ __align__(16) char buf[34816];
    bf16* lA = (bf16*)buf;                 // 8192 B
    bf16* lB = (bf16*)(buf + 8192);        // 8192 B
    bf16* sOut = (bf16*)buf;               // 34816 B overlay (epilogue only)
    int t = threadIdx.x;
    long bm = (long)blockIdx.y * 128;   // kd base
    long bn = (long)blockIdx.x * 128;   // window base
    int lane = t & 63;
    int wm = ((t >> 7) & 1) * 64;
    int wn = ((t >> 6) & 1) * 64;
    int l15 = lane & 15, quad = lane >> 4;

    f32x4 acc[4][4] = {};

    int rowA = t >> 2;
    int seg = (t & 3) * 8;
    const bf16* gA = At + (bm + rowA) * (long)K + seg;
    const bf16* gB = xn + (bn + rowA) * (long)K + seg;

    for (int k0 = 0; k0 < K; k0 += 32) {
        async16(&lA[t * 8], gA + k0);
        async16(&lA[2048 + t * 8], gA + (long)64 * K + k0);
        async16(&lB[t * 8], gB + k0);
        async16(&lB[2048 + t * 8], gB + (long)64 * K + k0);
        __syncthreads();
        bf16x8 af[4], bfr[4];
#pragma unroll
        for (int tm = 0; tm < 4; ++tm)
            af[tm] = *(const bf16x8*)&lA[(wm + tm * 16 + l15) * 32 + quad * 8];
#pragma unroll
        for (int tn = 0; tn < 4; ++tn)
            bfr[tn] = *(const bf16x8*)&lB[(wn + tn * 16 + l15) * 32 + quad * 8];
#pragma unroll
        for (int tm = 0; tm < 4; ++tm)
#pragma unroll
            for (int tn = 0; tn < 4; ++tn)
                acc[tm][tn] = __builtin_amdgcn_mfma_f32_16x16x32_bf16(
                    af[tm], bfr[tn], acc[tm][tn], 0, 0, 0);
        __syncthreads();
    }

    // epilogue: GELU, pack 4 consecutive kd -> LDS [win][kd] (pitch 136)
#pragma unroll
    for (int tn = 0; tn < 4; ++tn) {
        int win = wn + tn * 16 + l15;
#pragma unroll
        for (int tm = 0; tm < 4; ++tm) {
            int kd = wm + tm * 16 + quad * 4;
            bf16x4 p;
#pragma unroll
            for (int reg = 0; reg < 4; ++reg)
                p[reg] = (__bf16)gelu_fast(acc[tm][tn][reg]);
            *(bf16x4*)&sOut[win * 136 + kd] = p;
        }
    }
    __syncthreads();
#pragma unroll
    for (int it = 0; it < 8; ++it) {
        int id = it * 256 + t;
        int win = id >> 4, sg = id & 15;
        bf16x8 v = *(const bf16x8*)&sOut[win * 136 + sg * 8];
        *(bf16x8*)&g_[(bn + win) * 2048 + bm + sg * 8] = v;
    }
}

// ---------------- fused tail (transposed, 3 blocks/CU) ----------------------
// proj + bias + residual + LN2 + MLP (8 hidden chunks of 64, h in LDS) +
// bias + residual + un-permute + fp32 out (two 64-channel LDS passes).
__global__ __launch_bounds__(256, 3) void k_tail(
    const bf16* __restrict__ g_,   // (131072 x 128) token-major
    const bf16* __restrict__ wpT,  // (128 x 128)
    const float* __restrict__ bproj,
    const bf16* __restrict__ xt,   // residual (131072 x 128)
    const float* __restrict__ gamma2, const float* __restrict__ beta2,
    const bf16* __restrict__ w1T,  // (512 x 128)
    const float* __restrict__ b1,
    const bf16* __restrict__ w2T,  // (128 x 512)
    const float* __restrict__ b2,
    float* __restrict__ out)       // (8,128,128,128) fp32
{
    __shared__ __align__(16) char buf[53248];
    bf16* mpT = (bf16*)buf;                 // [token][channel] pitch 136 (34816 B)
    bf16* hT = (bf16*)(buf + 34816);        // [token][hid64] pitch 72 (18432 B)
    float* stats = (float*)(buf + 34816);   // overlay on hT (dead until chunks)
    float* outF = (float*)buf;              // [slot64][token] pitch 132 (overlay mpT)

    int t = threadIdx.x;
    long tb = (long)blockIdx.x * 128;
    int lane = t & 63;
    int wm = ((t >> 7) & 1) * 64;    // channel half (proj / mlp2 / epilogues)
    int wm1 = ((t >> 7) & 1) * 32;   // hidden half within a 64-chunk (mlp1)
    int wn = ((t >> 6) & 1) * 64;    // token half
    int l15 = lane & 15, quad = lane >> 4;
    int half = wm >> 6;

    int tok[4];
#pragma unroll
    for (int tn = 0; tn < 4; ++tn) tok[tn] = wn + tn * 16 + l15;

    // ---- proj (transposed): acc1[d][tok] = wpT @ g_^T ----
    f32x4 acc1[4][4] = {};
#pragma unroll
    for (int k0 = 0; k0 < 128; k0 += 32) {
        bf16x8 af[4], bfr[4];
#pragma unroll
        for (int tm = 0; tm < 4; ++tm)
            af[tm] = *(const bf16x8*)&wpT[(wm + tm * 16 + l15) * 128 + k0 + quad * 8];
#pragma unroll
        for (int tn = 0; tn < 4; ++tn)
            bfr[tn] = *(const bf16x8*)&g_[(tb + tok[tn]) * 128 + k0 + quad * 8];
#pragma unroll
        for (int tm = 0; tm < 4; ++tm)
#pragma unroll
            for (int tn = 0; tn < 4; ++tn)
                acc1[tm][tn] = __builtin_amdgcn_mfma_f32_16x16x32_bf16(
                    af[tm], bfr[tn], acc1[tm][tn], 0, 0, 0);
    }

    // ---- + bproj[channel] + xt[token][channel] ----
#pragma unroll
    for (int tm = 0; tm < 4; ++tm) {
        int c0 = wm + tm * 16 + quad * 4;
        float4 bp = *(const float4*)&bproj[c0];
#pragma unroll
        for (int tn = 0; tn < 4; ++tn) {
            bf16x4 xv = *(const bf16x4*)&xt[(tb + tok[tn]) * 128 + c0];
#pragma unroll
            for (int reg = 0; reg < 4; ++reg)
                acc1[tm][tn][reg] += ((const float*)&bp)[reg] + (float)xv[reg];
        }
    }

    // ---- LN2 stats ----
#pragma unroll
    for (int tn = 0; tn < 4; ++tn) {
        float s = 0.f, ss = 0.f;
#pragma unroll
        for (int tm = 0; tm < 4; ++tm)
#pragma unroll
            for (int reg = 0; reg < 4; ++reg) {
                float v = acc1[tm][tn][reg];
                s += v; ss += v * v;
            }
        s += __shfl_xor(s, 16); ss += __shfl_xor(ss, 16);
        s += __shfl_xor(s, 32); ss += __shfl_xor(ss, 32);
        if (quad == 0) {
            stats[tok[tn] * 2 + half] = s;
            stats[256 + tok[tn] * 2 + half] = ss;
        }
    }
    __syncthreads();

    // ---- LN apply -> mpT [token][channel] ----
    float mean[4], rstd[4];
#pragma unroll
    for (int tn = 0; tn < 4; ++tn) {
        float S = stats[tok[tn] * 2] + stats[tok[tn] * 2 + 1];
        float SS = stats[256 + tok[tn] * 2] + stats[256 + tok[tn] * 2 + 1];
        mean[tn] = S * (1.f / 128.f);
        float var = SS * (1.f / 128.f) - mean[tn] * mean[tn];
        rstd[tn] = rsqrtf(var + 1e-5f);
    }
#pragma unroll
    for (int tm = 0; tm < 4; ++tm) {
        int c0 = wm + tm * 16 + quad * 4;
        float4 gv = *(const float4*)&gamma2[c0];
        float4 bv = *(const float4*)&beta2[c0];
#pragma unroll
        for (int tn = 0; tn < 4; ++tn) {
            bf16x4 p;
#pragma unroll
            for (int reg = 0; reg < 4; ++reg)
                p[reg] = (__bf16)((acc1[tm][tn][reg] - mean[tn]) * rstd[tn] *
                                      ((const float*)&gv)[reg] +
                                  ((const float*)&bv)[reg]);
            *(bf16x4*)&mpT[tok[tn] * 136 + c0] = p;
        }
    }
    __syncthreads();

    // ---- MLP: 8 hidden chunks of 64; h chunk (18 KB) stays in LDS ----
    f32x4 acc2[4][4] = {};
    for (int oh = 0; oh < 8; ++oh) {
        f32x4 acch[2][4] = {};
#pragma unroll
        for (int k0 = 0; k0 < 128; k0 += 32) {
            bf16x8 af[2], bfr[4];
#pragma unroll
            for (int tm = 0; tm < 2; ++tm)
                af[tm] = *(const bf16x8*)&w1T[(oh * 64 + wm1 + tm * 16 + l15) * 128 +
                                              k0 + quad * 8];
#pragma unroll
            for (int tn = 0; tn < 4; ++tn)
                bfr[tn] = *(const bf16x8*)&mpT[tok[tn] * 136 + k0 + quad * 8];
#pragma unroll
            for (int tm = 0; tm < 2; ++tm)
#pragma unroll
                for (int tn = 0; tn < 4; ++tn)
                    acch[tm][tn] = __builtin_amdgcn_mfma_f32_16x16x32_bf16(
                        af[tm], bfr[tn], acch[tm][tn], 0, 0, 0);
        }
        // GELU + b1 -> hT [token][hid64] pitch 72
#pragma unroll
        for (int tm = 0; tm < 2; ++tm) {
            int hc0 = wm1 + tm * 16 + quad * 4;   // local hidden in [0,64)
            float4 bh = *(const float4*)&b1[oh * 64 + hc0];
#pragma unroll
            for (int tn = 0; tn < 4; ++tn) {
                bf16x4 p;
#pragma unroll
                for (int reg = 0; reg < 4; ++reg)
                    p[reg] = (__bf16)gelu_fast(acch[tm][tn][reg] +
                                               ((const float*)&bh)[reg]);
                *(bf16x4*)&hT[tok[tn] * 72 + hc0] = p;
            }
        }
        __syncthreads();
        // MLP2 partial: acc2 += w2T-chunk @ hT^T  (K = 64)
#pragma unroll
        for (int k0 = 0; k0 < 64; k0 += 32) {
            bf16x8 af[4], bfr[4];
#pragma unroll
            for (int tm = 0; tm < 4; ++tm)
                af[tm] = *(const bf16x8*)&w2T[(wm + tm * 16 + l15) * 512 +
                                              oh * 64 + k0 + quad * 8];
#pragma unroll
            for (int tn = 0; tn < 4; ++tn)
                bfr[tn] = *(const bf16x8*)&hT[tok[tn] * 72 + k0 + quad * 8];
#pragma unroll
            for (int tm = 0; tm < 4; ++tm)
#pragma unroll
                for (int tn = 0; tn < 4; ++tn)
                    acc2[tm][tn] = __builtin_amdgcn_mfma_f32_16x16x32_bf16(
                        af[tm], bfr[tn], acc2[tm][tn], 0, 0, 0);
        }
        __syncthreads();
    }

    // ---- final: out = y2 + mlp2 + b2 in two 64-channel LDS passes ----
    long win0 = tb >> 4;
    int b = (int)(win0 >> 10);
    int hq = (int)(win0 >> 5) & 31;
    int wq0 = (int)win0 & 31;
#pragma unroll
    for (int p = 0; p < 2; ++p) {
#pragma unroll
        for (int tmi = 0; tmi < 2; ++tmi) {
            int tm = p * 2 + tmi;
            int c0 = wm + tm * 16 + quad * 4;
            int slot0 = (wm >> 1) + tmi * 16 + quad * 4;
            float4 bv = *(const float4*)&b2[c0];
#pragma unroll
            for (int tn = 0; tn < 4; ++tn)
#pragma unroll
                for (int reg = 0; reg < 4; ++reg)
                    outF[(slot0 + reg) * 132 + tok[tn]] =
                        acc1[tm][tn][reg] + acc2[tm][tn][reg] +
                        ((const float*)&bv)[reg];
        }
        __syncthreads();
#pragma unroll
        for (int it = 0; it < 8; ++it) {
            int id = it * 256 + t;
            int slot = id >> 5, rem = id & 31;
            int rr = rem >> 3, wqo = rem & 7;
            int c = slot + ((slot >= 32) ? 32 : 0) + p * 32;
            f32x4 v = *(const f32x4*)&outF[slot * 132 + wqo * 16 + rr * 4];
            long addr = (((long)b * 128 + c) * 128 + hq * 4 + rr) * 128 +
                        (wq0 + wqo) * 4;
            *(f32x4*)&out[addr] = v;
        }
        __syncthreads();
    }
}

extern "C" void kernel_launch(void* const* d_in, const int* in_sizes, int n_in,
                              void* d_out, int out_size, void* d_ws, size_t ws_size,
                              hipStream_t stream) {
    const float* x      = (const float*)d_in[0];
    const float* gamma1 = (const float*)d_in[1];
    const float* beta1  = (const float*)d_in[2];
    const float* sed_w  = (const float*)d_in[3];
    const float* w_proj = (const float*)d_in[4];
    const float* b_proj = (const float*)d_in[5];
    const float* gamma2 = (const float*)d_in[6];
    const float* beta2  = (const float*)d_in[7];
    const float* w1     = (const float*)d_in[8];
    const float* b1     = (const float*)d_in[9];
    const float* w2     = (const float*)d_in[10];
    const float* b2     = (const float*)d_in[11];

    char* ws = (char*)d_ws;
    bf16* At  = (bf16*)(ws + 0);           //  8,388,608
    bf16* wpT = (bf16*)(ws + 8388608);     //     32,768
    bf16* w1T = (bf16*)(ws + 8421376);     //    131,072
    bf16* w2T = (bf16*)(ws + 8552448);     //    131,072
    bf16* xt  = (bf16*)(ws + 8683520);     // 33,554,432
    bf16* xn  = (bf16*)(ws + 42237952);    // 33,554,432
    bf16* g_  = (bf16*)(ws + 75792384);    // 33,554,432

    hipLaunchKernelGGL(k_prep_w, dim3(576), dim3(256), 0, stream,
                       w_proj, w1, w2, wpT, w1T, w2T);
    hipLaunchKernelGGL(k_prep_A, dim3(256), dim3(256), 0, stream, sed_w, At);
    hipLaunchKernelGGL(k_ln1, dim3(1024), dim3(256), 0, stream,
                       x, gamma1, beta1, xt, xn);
    // SED (transposed): D[kd][win]; grid x = 8192/128 windows, y = 2048/128 kd
    hipLaunchKernelGGL(k_gemm_sed, dim3(64, 16), dim3(256), 0, stream,
                       At, xn, g_);
    // fused tail: proj + res + LN2 + MLP + res + un-permute + fp32 out
    hipLaunchKernelGGL(k_tail, dim3(1024), dim3(256), 0, stream,
                       g_, wpT, b_proj, xt, gamma2, beta2,
                       w1T, b1, w2T, b2, (float*)d_out);
}

// Round 6
// 350.759 us; speedup vs baseline: 1.6211x; 1.1415x over previous
//
#include <hip/hip_runtime.h>
#include <hip/hip_bf16.h>

#define DEVI __device__ __forceinline__

typedef __attribute__((ext_vector_type(8))) __bf16 bf16x8;
typedef __attribute__((ext_vector_type(4))) __bf16 bf16x4;
typedef __attribute__((ext_vector_type(4))) float f32x4;

using bf16 = __hip_bfloat16;

DEVI float bf2f(bf16 v) { return __bfloat162float(v); }
DEVI bf16 f2bf(float v) { return __float2bfloat16(v); }

// tanh-form GELU; max |diff vs exact| ~3e-3, under bf16 epilogue noise.
DEVI float gelu_fast(float v) {
    float t = v * (2.30220777f + 0.10294322f * v * v);
    float e = __builtin_amdgcn_exp2f(t);
    return v - v * __builtin_amdgcn_rcpf(e + 1.0f);
}

DEVI void async16(void* lds, const void* g) {
    __builtin_amdgcn_global_load_lds(
        (const __attribute__((address_space(1))) void*)g,
        (__attribute__((address_space(3))) void*)lds, 16, 0, 0);
}

// sign of e_i * e_j in 16-dim Cayley-Dickson algebra (index is i^j)
DEVI int cd_sign(int i, int j) {
    int s = 1, n = 16;
    while (n > 1) {
        int h = n >> 1;
        int ih = (i >= h), jh = (j >= h);
        if (!ih && !jh) {
        } else if (!ih && jh) {
            int ni = j - h, nj = i;
            i = ni; j = nj;
        } else if (ih && !jh) {
            if (j != 0) s = -s;
            i = i - h;
        } else {
            int ni = j - h, nj = i - h;
            if (ni == 0) s = -s;
            i = ni; j = nj;
        }
        n = h;
    }
    return s;
}

// ---------------- prep: build A_T (2048x2048 bf16), row (k,d), col (i,c) ----
__global__ __launch_bounds__(256) void k_prep_A(const float* __restrict__ sed_w,
                                                bf16* __restrict__ At) {
    __shared__ float tile[128][129];
    int bi = blockIdx.x;  // 0..255
    int i = bi >> 4, k = bi & 15;
    int j = i ^ k;
    float s = (float)cd_sign(i, j);
    int t = threadIdx.x;
    int lo = t & 127, hi = t >> 7;
    const float* src = sed_w + j * 16384;
    for (int it = 0; it < 64; ++it) {
        int c = it * 2 + hi;
        tile[c][lo] = src[c * 128 + lo];
    }
    __syncthreads();
    for (int it = 0; it < 64; ++it) {
        int d = it * 2 + hi;
        At[(long)(k * 128 + d) * 2048 + i * 128 + lo] = f2bf(s * tile[lo][d]);
    }
}

// ---------------- prep: bf16 transposed weights -----------------------------
__global__ __launch_bounds__(256) void k_prep_w(const float* __restrict__ wp,
                                                const float* __restrict__ w1,
                                                const float* __restrict__ w2,
                                                bf16* __restrict__ wpT,
                                                bf16* __restrict__ w1T,
                                                bf16* __restrict__ w2T) {
    int idx = blockIdx.x * 256 + threadIdx.x;
    if (idx < 16384) {
        int d = idx >> 7, c = idx & 127;
        wpT[idx] = f2bf(wp[c * 128 + d]);              // wpT[d][c] = wp[c][d]
    } else if (idx < 16384 + 65536) {
        int e = idx - 16384;
        int o = e >> 7, c = e & 127;
        w1T[e] = f2bf(w1[c * 512 + o]);                // w1T[o][c] = w1[c][o]
    } else if (idx < 16384 + 131072) {
        int e = idx - 81920;
        int o = e >> 9, c = e & 511;
        w2T[e] = f2bf(w2[c * 128 + o]);                // w2T[o][c] = w2[c][o]
    }
}

// ---------------- LN1 + transpose to window-permuted token order ------------
__global__ __launch_bounds__(256) void k_ln1(const float* __restrict__ x,
                                             const float* __restrict__ g,
                                             const float* __restrict__ bta,
                                             bf16* __restrict__ xt,
                                             bf16* __restrict__ xn) {
    __shared__ float tile[128][128];   // [ch][c]
    __shared__ float ps[2][128], pss[2][128];
    int b = blockIdx.x >> 7, r = blockIdx.x & 127;
    int t = threadIdx.x, c = t & 127, half = t >> 7;
    const float* xb = x + ((long)b * 128 * 128 + r) * 128;
    for (int it = 0; it < 64; ++it) {
        int ch = it * 2 + half;
        tile[ch][c] = xb[(long)ch * 16384 + c];
    }
    __syncthreads();
    float s = 0.f, ss = 0.f;
    for (int ch = half * 64; ch < half * 64 + 64; ++ch) {
        float v = tile[ch][c];
        s += v; ss += v * v;
    }
    ps[half][c] = s; pss[half][c] = ss;
    __syncthreads();
    float S = ps[0][c] + ps[1][c], SS = pss[0][c] + pss[1][c];
    float mean = S * (1.f / 128.f);
    float var = SS * (1.f / 128.f) - mean * mean;
    float rstd = rsqrtf(var + 1e-5f);
    long n = (((long)b * 32 + (r >> 2)) * 32 + (c >> 2)) * 16 + ((r & 3) * 4 + (c & 3));
    bf16* xtr = xt + n * 128 + half * 64;
    bf16* xnr = xn + n * 128 + half * 64;
#pragma unroll
    for (int v8 = 0; v8 < 8; ++v8) {
        bf16x8 pt, pn;
#pragma unroll
        for (int e = 0; e < 8; ++e) {
            int ch = half * 64 + v8 * 8 + e;
            float v = tile[ch][c];
            pt[e] = (__bf16)v;
            pn[e] = (__bf16)((v - mean) * rstd * g[ch] + bta[ch]);
        }
        *(bf16x8*)&xtr[v8 * 8] = pt;
        *(bf16x8*)&xnr[v8 * 8] = pn;
    }
}

// ---------------- SED GEMM (transposed): D[kd][win] = At @ xn^T -------------
// launch_bounds (256,3): 170-reg cap >= ~140 live, no spill, 3 blocks/CU.
__global__ __launch_bounds__(256, 3) void k_gemm_sed(const bf16* __restrict__ At,
                                                     const bf16* __restrict__ xn,
                                                     bf16* __restrict__ g_) {
    const int K = 2048;
    __shared__ __align__(16) char buf[34816];
    bf16* lA = (bf16*)buf;                 // 8192 B
    bf16* lB = (bf16*)(buf + 8192);        // 8192 B
    bf16* sOut = (bf16*)buf;               // 34816 B overlay (epilogue only)
    int t = threadIdx.x;
    long bm = (long)blockIdx.y * 128;   // kd base
    long bn = (long)blockIdx.x * 128;   // window base
    int lane = t & 63;
    int wm = ((t >> 7) & 1) * 64;
    int wn = ((t >> 6) & 1) * 64;
    int l15 = lane & 15, quad = lane >> 4;

    f32x4 acc[4][4] = {};

    int rowA = t >> 2;
    int seg = (t & 3) * 8;
    const bf16* gA = At + (bm + rowA) * (long)K + seg;
    const bf16* gB = xn + (bn + rowA) * (long)K + seg;

    for (int k0 = 0; k0 < K; k0 += 32) {
        async16(&lA[t * 8], gA + k0);
        async16(&lA[2048 + t * 8], gA + (long)64 * K + k0);
        async16(&lB[t * 8], gB + k0);
        async16(&lB[2048 + t * 8], gB + (long)64 * K + k0);
        __syncthreads();
        bf16x8 af[4], bfr[4];
#pragma unroll
        for (int tm = 0; tm < 4; ++tm)
            af[tm] = *(const bf16x8*)&lA[(wm + tm * 16 + l15) * 32 + quad * 8];
#pragma unroll
        for (int tn = 0; tn < 4; ++tn)
            bfr[tn] = *(const bf16x8*)&lB[(wn + tn * 16 + l15) * 32 + quad * 8];
#pragma unroll
        for (int tm = 0; tm < 4; ++tm)
#pragma unroll
            for (int tn = 0; tn < 4; ++tn)
                acc[tm][tn] = __builtin_amdgcn_mfma_f32_16x16x32_bf16(
                    af[tm], bfr[tn], acc[tm][tn], 0, 0, 0);
        __syncthreads();
    }

    // epilogue: GELU, pack 4 consecutive kd -> LDS [win][kd] (pitch 136)
#pragma unroll
    for (int tn = 0; tn < 4; ++tn) {
        int win = wn + tn * 16 + l15;
#pragma unroll
        for (int tm = 0; tm < 4; ++tm) {
            int kd = wm + tm * 16 + quad * 4;
            bf16x4 p;
#pragma unroll
            for (int reg = 0; reg < 4; ++reg)
                p[reg] = (__bf16)gelu_fast(acc[tm][tn][reg]);
            *(bf16x4*)&sOut[win * 136 + kd] = p;
        }
    }
    __syncthreads();
#pragma unroll
    for (int it = 0; it < 8; ++it) {
        int id = it * 256 + t;
        int win = id >> 4, sg = id & 15;
        bf16x8 v = *(const bf16x8*)&sOut[win * 136 + sg * 8];
        *(bf16x8*)&g_[(bn + win) * 2048 + bm + sg * 8] = v;
    }
}

// ---------------- fused tail (transposed, 2 blocks/CU, no spill) ------------
// proj + bias + residual + LN2 + MLP (8 hidden chunks of 64, double-buffered
// hT, ONE barrier per chunk) + bias + residual + un-permute + fp32 out.
__global__ __launch_bounds__(256, 2) void k_tail(
    const bf16* __restrict__ g_,   // (131072 x 128) token-major
    const bf16* __restrict__ wpT,  // (128 x 128)
    const float* __restrict__ bproj,
    const bf16* __restrict__ xt,   // residual (131072 x 128)
    const float* __restrict__ gamma2, const float* __restrict__ beta2,
    const bf16* __restrict__ w1T,  // (512 x 128)
    const float* __restrict__ b1,
    const bf16* __restrict__ w2T,  // (128 x 512)
    const float* __restrict__ b2,
    float* __restrict__ out)       // (8,128,128,128) fp32
{
    __shared__ __align__(16) char buf[71680];
    bf16* mpT = (bf16*)buf;                 // [token][channel] pitch 136 (34816 B)
    float* stats = (float*)(buf + 34816);   // overlay on hT0 (dead until chunks)
    float* outF = (float*)buf;              // [slot64][token] pitch 132 (overlay mpT)

    int t = threadIdx.x;
    long tb = (long)blockIdx.x * 128;
    int lane = t & 63;
    int wm = ((t >> 7) & 1) * 64;    // channel half (proj / mlp2 / epilogues)
    int wm1 = ((t >> 7) & 1) * 32;   // hidden half within a 64-chunk (mlp1)
    int wn = ((t >> 6) & 1) * 64;    // token half
    int l15 = lane & 15, quad = lane >> 4;
    int half = wm >> 6;

    int tok[4];
#pragma unroll
    for (int tn = 0; tn < 4; ++tn) tok[tn] = wn + tn * 16 + l15;

    // ---- proj (transposed): acc1[d][tok] = wpT @ g_^T ----
    f32x4 acc1[4][4] = {};
#pragma unroll
    for (int k0 = 0; k0 < 128; k0 += 32) {
        bf16x8 af[4], bfr[4];
#pragma unroll
        for (int tm = 0; tm < 4; ++tm)
            af[tm] = *(const bf16x8*)&wpT[(wm + tm * 16 + l15) * 128 + k0 + quad * 8];
#pragma unroll
        for (int tn = 0; tn < 4; ++tn)
            bfr[tn] = *(const bf16x8*)&g_[(tb + tok[tn]) * 128 + k0 + quad * 8];
#pragma unroll
        for (int tm = 0; tm < 4; ++tm)
#pragma unroll
            for (int tn = 0; tn < 4; ++tn)
                acc1[tm][tn] = __builtin_amdgcn_mfma_f32_16x16x32_bf16(
                    af[tm], bfr[tn], acc1[tm][tn], 0, 0, 0);
    }

    // ---- + bproj[channel] + xt[token][channel] ----
#pragma unroll
    for (int tm = 0; tm < 4; ++tm) {
        int c0 = wm + tm * 16 + quad * 4;
        float4 bp = *(const float4*)&bproj[c0];
#pragma unroll
        for (int tn = 0; tn < 4; ++tn) {
            bf16x4 xv = *(const bf16x4*)&xt[(tb + tok[tn]) * 128 + c0];
#pragma unroll
            for (int reg = 0; reg < 4; ++reg)
                acc1[tm][tn][reg] += ((const float*)&bp)[reg] + (float)xv[reg];
        }
    }

    // ---- LN2 stats ----
#pragma unroll
    for (int tn = 0; tn < 4; ++tn) {
        float s = 0.f, ss = 0.f;
#pragma unroll
        for (int tm = 0; tm < 4; ++tm)
#pragma unroll
            for (int reg = 0; reg < 4; ++reg) {
                float v = acc1[tm][tn][reg];
                s += v; ss += v * v;
            }
        s += __shfl_xor(s, 16); ss += __shfl_xor(ss, 16);
        s += __shfl_xor(s, 32); ss += __shfl_xor(ss, 32);
        if (quad == 0) {
            stats[tok[tn] * 2 + half] = s;
            stats[256 + tok[tn] * 2 + half] = ss;
        }
    }
    __syncthreads();

    // ---- LN apply -> mpT [token][channel] ----
    float mean[4], rstd[4];
#pragma unroll
    for (int tn = 0; tn < 4; ++tn) {
        float S = stats[tok[tn] * 2] + stats[tok[tn] * 2 + 1];
        float SS = stats[256 + tok[tn] * 2] + stats[256 + tok[tn] * 2 + 1];
        mean[tn] = S * (1.f / 128.f);
        float var = SS * (1.f / 128.f) - mean[tn] * mean[tn];
        rstd[tn] = rsqrtf(var + 1e-5f);
    }
#pragma unroll
    for (int tm = 0; tm < 4; ++tm) {
        int c0 = wm + tm * 16 + quad * 4;
        float4 gv = *(const float4*)&gamma2[c0];
        float4 bv = *(const float4*)&beta2[c0];
#pragma unroll
        for (int tn = 0; tn < 4; ++tn) {
            bf16x4 p;
#pragma unroll
            for (int reg = 0; reg < 4; ++reg)
                p[reg] = (__bf16)((acc1[tm][tn][reg] - mean[tn]) * rstd[tn] *
                                      ((const float*)&gv)[reg] +
                                  ((const float*)&bv)[reg]);
            *(bf16x4*)&mpT[tok[tn] * 136 + c0] = p;
        }
    }
    __syncthreads();

    // ---- MLP: 8 hidden chunks of 64; double-buffered hT, 1 barrier/chunk ----
    f32x4 acc2[4][4] = {};
    for (int oh = 0; oh < 8; ++oh) {
        bf16* hT = (bf16*)(buf + 34816 + (oh & 1) * 18432);  // pitch 72
        f32x4 acch[2][4] = {};
#pragma unroll
        for (int k0 = 0; k0 < 128; k0 += 32) {
            bf16x8 af[2], bfr[4];
#pragma unroll
            for (int tm = 0; tm < 2; ++tm)
                af[tm] = *(const bf16x8*)&w1T[(oh * 64 + wm1 + tm * 16 + l15) * 128 +
                                              k0 + quad * 8];
#pragma unroll
            for (int tn = 0; tn < 4; ++tn)
                bfr[tn] = *(const bf16x8*)&mpT[tok[tn] * 136 + k0 + quad * 8];
#pragma unroll
            for (int tm = 0; tm < 2; ++tm)
#pragma unroll
                for (int tn = 0; tn < 4; ++tn)
                    acch[tm][tn] = __builtin_amdgcn_mfma_f32_16x16x32_bf16(
                        af[tm], bfr[tn], acch[tm][tn], 0, 0, 0);
        }
        // GELU + b1 -> hT [token][hid64] pitch 72
#pragma unroll
        for (int tm = 0; tm < 2; ++tm) {
            int hc0 = wm1 + tm * 16 + quad * 4;   // local hidden in [0,64)
            float4 bh = *(const float4*)&b1[oh * 64 + hc0];
#pragma unroll
            for (int tn = 0; tn < 4; ++tn) {
                bf16x4 p;
#pragma unroll
                for (int reg = 0; reg < 4; ++reg)
                    p[reg] = (__bf16)gelu_fast(acch[tm][tn][reg] +
                                               ((const float*)&bh)[reg]);
                *(bf16x4*)&hT[tok[tn] * 72 + hc0] = p;
            }
        }
        __syncthreads();
        // MLP2 partial: acc2 += w2T-chunk @ hT^T  (K = 64)
#pragma unroll
        for (int k0 = 0; k0 < 64; k0 += 32) {
            bf16x8 af[4], bfr[4];
#pragma unroll
            for (int tm = 0; tm < 4; ++tm)
                af[tm] = *(const bf16x8*)&w2T[(wm + tm * 16 + l15) * 512 +
                                              oh * 64 + k0 + quad * 8];
#pragma unroll
            for (int tn = 0; tn < 4; ++tn)
                bfr[tn] = *(const bf16x8*)&hT[tok[tn] * 72 + k0 + quad * 8];
#pragma unroll
            for (int tm = 0; tm < 4; ++tm)
#pragma unroll
                for (int tn = 0; tn < 4; ++tn)
                    acc2[tm][tn] = __builtin_amdgcn_mfma_f32_16x16x32_bf16(
                        af[tm], bfr[tn], acc2[tm][tn], 0, 0, 0);
        }
        // no second barrier: next chunk writes the other hT buffer
    }
    __syncthreads();

    // ---- final: out = y2 + mlp2 + b2 in two 64-channel LDS passes ----
    long win0 = tb >> 4;
    int b = (int)(win0 >> 10);
    int hq = (int)(win0 >> 5) & 31;
    int wq0 = (int)win0 & 31;
#pragma unroll
    for (int p = 0; p < 2; ++p) {
#pragma unroll
        for (int tmi = 0; tmi < 2; ++tmi) {
            int tm = p * 2 + tmi;
            int c0 = wm + tm * 16 + quad * 4;
            int slot0 = (wm >> 1) + tmi * 16 + quad * 4;
            float4 bv = *(const float4*)&b2[c0];
#pragma unroll
            for (int tn = 0; tn < 4; ++tn)
#pragma unroll
                for (int reg = 0; reg < 4; ++reg)
                    outF[(slot0 + reg) * 132 + tok[tn]] =
                        acc1[tm][tn][reg] + acc2[tm][tn][reg] +
                        ((const float*)&bv)[reg];
        }
        __syncthreads();
#pragma unroll
        for (int it = 0; it < 8; ++it) {
            int id = it * 256 + t;
            int slot = id >> 5, rem = id & 31;
            int rr = rem >> 3, wqo = rem & 7;
            int c = slot + ((slot >= 32) ? 32 : 0) + p * 32;
            f32x4 v = *(const f32x4*)&outF[slot * 132 + wqo * 16 + rr * 4];
            long addr = (((long)b * 128 + c) * 128 + hq * 4 + rr) * 128 +
                        (wq0 + wqo) * 4;
            *(f32x4*)&out[addr] = v;
        }
        __syncthreads();
    }
}

extern "C" void kernel_launch(void* const* d_in, const int* in_sizes, int n_in,
                              void* d_out, int out_size, void* d_ws, size_t ws_size,
                              hipStream_t stream) {
    const float* x      = (const float*)d_in[0];
    const float* gamma1 = (const float*)d_in[1];
    const float* beta1  = (const float*)d_in[2];
    const float* sed_w  = (const float*)d_in[3];
    const float* w_proj = (const float*)d_in[4];
    const float* b_proj = (const float*)d_in[5];
    const float* gamma2 = (const float*)d_in[6];
    const float* beta2  = (const float*)d_in[7];
    const float* w1     = (const float*)d_in[8];
    const float* b1     = (const float*)d_in[9];
    const float* w2     = (const float*)d_in[10];
    const float* b2     = (const float*)d_in[11];

    char* ws = (char*)d_ws;
    bf16* At  = (bf16*)(ws + 0);           //  8,388,608
    bf16* wpT = (bf16*)(ws + 8388608);     //     32,768
    bf16* w1T = (bf16*)(ws + 8421376);     //    131,072
    bf16* w2T = (bf16*)(ws + 8552448);     //    131,072
    bf16* xt  = (bf16*)(ws + 8683520);     // 33,554,432
    bf16* xn  = (bf16*)(ws + 42237952);    // 33,554,432
    bf16* g_  = (bf16*)(ws + 75792384);    // 33,554,432

    hipLaunchKernelGGL(k_prep_w, dim3(576), dim3(256), 0, stream,
                       w_proj, w1, w2, wpT, w1T, w2T);
    hipLaunchKernelGGL(k_prep_A, dim3(256), dim3(256), 0, stream, sed_w, At);
    hipLaunchKernelGGL(k_ln1, dim3(1024), dim3(256), 0, stream,
                       x, gamma1, beta1, xt, xn);
    // SED (transposed): D[kd][win]; grid x = 8192/128 windows, y = 2048/128 kd
    hipLaunchKernelGGL(k_gemm_sed, dim3(64, 16), dim3(256), 0, stream,
                       At, xn, g_);
    // fused tail: proj + res + LN2 + MLP + res + un-permute + fp32 out
    hipLaunchKernelGGL(k_tail, dim3(1024), dim3(256), 0, stream,
                       g_, wpT, b_proj, xt, gamma2, beta2,
                       w1T, b1, w2T, b2, (float*)d_out);
}